// Round 1
// baseline (399.939 us; speedup 1.0000x reference)
//
#include <hip/hip_runtime.h>
#include <hip/hip_bf16.h>
#include <hip/hip_fp16.h>

#define N_TOKENS 16384
#define D_IN 768
#define N_EXPERTS 8
#define EXPERT_DIM 2048

#define ROUTER_BLOCKS 256
#define TOK_PER_BLOCK 64

typedef _Float16 half8 __attribute__((ext_vector_type(8)));
typedef float floatx4 __attribute__((ext_vector_type(4)));

#define BM 128
#define BN 128
#define BK 32
#define NBUF 3
// LDS tiles: UNPADDED 128x32 halves (64B rows), triple-buffered (prefetch depth 2).
// Swizzle: 16B chunk c of row r stored at chunk (c + (r>>1)) & 3 -> frag
// ds_read_b128 conflict-free (verified: SQ_LDS_BANK_CONFLICT == 0 in r3/r4).

// s_waitcnt imm (gfx9): vmcnt[3:0] | expcnt<<4 | lgkmcnt<<8 | vmcnt[5:4]<<14
#define WAIT_VM8 0xF78   // vmcnt(8)  : tiles k+1,k+2 in flight, tile k landed
#define WAIT_VM4 0xF74   // vmcnt(4)
#define WAIT_VM0 0xF70   // vmcnt(0)

__device__ __forceinline__ void glds16(const _Float16* g, _Float16* l) {
    __builtin_amdgcn_global_load_lds(
        (const __attribute__((address_space(1))) unsigned int*)g,
        (__attribute__((address_space(3))) unsigned int*)l, 16, 0, 0);
}

// ---------------- act fp32 -> f16 (one-time) ----------------
__global__ __launch_bounds__(256) void convert_act(const float* __restrict__ act,
    _Float16* __restrict__ act_h)
{
    size_t i = ((size_t)blockIdx.x * 256 + threadIdx.x) * 8;
    float4 v0 = *(const float4*)(act + i);
    float4 v1 = *(const float4*)(act + i + 4);
    half8 h;
    h[0] = (_Float16)v0.x; h[1] = (_Float16)v0.y; h[2] = (_Float16)v0.z; h[3] = (_Float16)v0.w;
    h[4] = (_Float16)v1.x; h[5] = (_Float16)v1.y; h[6] = (_Float16)v1.z; h[7] = (_Float16)v1.w;
    *(half8*)(act_h + i) = h;
}

// ---------------- Phase 1: router (fp32: argmax is a decision, keep exact) ----------------
__global__ __launch_bounds__(256) void router_kernel(const float* __restrict__ act,
    const float* __restrict__ router_b, const float* __restrict__ router,
    float* __restrict__ prob, int* __restrict__ localpos, int* __restrict__ eidx,
    int* __restrict__ hist)
{
    __shared__ int h[N_EXPERTS];
    if (threadIdx.x < N_EXPERTS) h[threadIdx.x] = 0;
    __syncthreads();

    int wave = threadIdx.x >> 6, lane = threadIdx.x & 63;
#pragma unroll 1
    for (int it = 0; it < 16; ++it) {
        int t = blockIdx.x * TOK_PER_BLOCK + wave * 16 + it;
        float acc[8];
#pragma unroll
        for (int e = 0; e < 8; ++e) acc[e] = 0.f;
        const float* arow = act + (size_t)t * D_IN;
#pragma unroll
        for (int i0 = 0; i0 < D_IN; i0 += 64) {
            int i = i0 + lane;
            float a = arow[i] - router_b[i];
            const float* r = router + i * 8;
#pragma unroll
            for (int e = 0; e < 8; ++e) acc[e] += a * r[e];
        }
#pragma unroll
        for (int s = 32; s > 0; s >>= 1) {
#pragma unroll
            for (int e = 0; e < 8; ++e) acc[e] += __shfl_down(acc[e], s, 64);
        }
        if (lane == 0) {
            float m = acc[0]; int ai = 0;
#pragma unroll
            for (int e = 1; e < 8; ++e) if (acc[e] > m) { m = acc[e]; ai = e; }
            float s = 0.f;
#pragma unroll
            for (int e = 0; e < 8; ++e) s += __expf(acc[e] - m);
            prob[t] = 1.0f / s;
            eidx[t] = ai;
            localpos[t] = atomicAdd(&h[ai], 1);
        }
    }
    __syncthreads();
    if (threadIdx.x < N_EXPERTS) hist[blockIdx.x * N_EXPERTS + threadIdx.x] = h[threadIdx.x];
}

// ---------------- Phase 2: scan ----------------
__global__ __launch_bounds__(256) void scan_kernel(int* __restrict__ hist,
    int* __restrict__ counts, int* __restrict__ offsets)
{
    __shared__ int sh[ROUTER_BLOCKS * N_EXPERTS];
    __shared__ int tot[N_EXPERTS], off[N_EXPERTS];
    int tid = threadIdx.x;
    *(int4*)&sh[tid * 8]     = *(const int4*)&hist[tid * 8];
    *(int4*)&sh[tid * 8 + 4] = *(const int4*)&hist[tid * 8 + 4];
    __syncthreads();
    if (tid < N_EXPERTS) {
        int run = 0;
        for (int b = 0; b < ROUTER_BLOCKS; ++b) {
            int v = sh[b * 8 + tid];
            sh[b * 8 + tid] = run;
            run += v;
        }
        tot[tid] = run;
    }
    __syncthreads();
    if (tid == 0) {
        int run = 0;
        for (int e = 0; e < N_EXPERTS; ++e) {
            off[e] = run; offsets[e] = run; counts[e] = tot[e]; run += tot[e];
        }
    }
    __syncthreads();
    int4 a = *(const int4*)&sh[tid * 8];
    int4 b = *(const int4*)&sh[tid * 8 + 4];
    a.x += off[0]; a.y += off[1]; a.z += off[2]; a.w += off[3];
    b.x += off[4]; b.y += off[5]; b.z += off[6]; b.w += off[7];
    *(int4*)&hist[tid * 8]     = a;
    *(int4*)&hist[tid * 8 + 4] = b;
}

// ---------------- Phase 3: scatter ----------------
__global__ __launch_bounds__(256) void order_kernel(const int* __restrict__ eidx,
    const int* __restrict__ localpos, const int* __restrict__ hist,
    int* __restrict__ order)
{
    int t = blockIdx.x * 256 + threadIdx.x;
    int base = hist[(t >> 6) * N_EXPERTS + eidx[t]];
    order[base + localpos[t]] = t;
}

// ---------------- Weight transpose fp32 [E][K][Nc] -> f16 [E][Nc][K] ----------------
__global__ __launch_bounds__(256) void transpose_to_half(const float* __restrict__ W,
    _Float16* __restrict__ WT, int K, int Nc)
{
    __shared__ _Float16 tile[64][72];
    size_t esz = (size_t)K * Nc;
    const float* We = W + (size_t)blockIdx.z * esz;
    _Float16* WTe = WT + (size_t)blockIdx.z * esz;
    int n0 = blockIdx.x * 64, k0 = blockIdx.y * 64;
    int tr = threadIdx.x >> 4;
    int tc = threadIdx.x & 15;
#pragma unroll
    for (int rr = 0; rr < 64; rr += 16) {
        int k = k0 + rr + tr;
        float4 v = *(const float4*)(We + (size_t)k * Nc + n0 + tc * 4);
        tile[tc * 4 + 0][rr + tr] = (_Float16)v.x;
        tile[tc * 4 + 1][rr + tr] = (_Float16)v.y;
        tile[tc * 4 + 2][rr + tr] = (_Float16)v.z;
        tile[tc * 4 + 3][rr + tr] = (_Float16)v.w;
    }
    __syncthreads();
#pragma unroll
    for (int p = 0; p < 2; ++p) {
        int id = threadIdx.x + p * 256;
        int r = id >> 3, ch = id & 7;
        half8 v = *(const half8*)&tile[r][ch * 8];
        *(half8*)(WTe + (size_t)(n0 + r) * K + k0 + ch * 8) = v;
    }
}

// ---------------- Encode GEMM (triple-buffered, depth-2 prefetch, XCD swizzle) ----------------
// 1D grid 16384: xcd = id&7, r = id>>3; group_within = r>>7 (16), mt = r&127;
// P = xcd + 8*group_within in [0,128): e = P>>4, nt = P&15.
// All mt-blocks of one (e,nt) land on one XCD -> B tile (196KB) L2-resident.
__global__ __launch_bounds__(256) void encode_kernel(const _Float16* __restrict__ act_h,
    const _Float16* __restrict__ encT, const int* __restrict__ order,
    const int* __restrict__ counts, const int* __restrict__ offsets,
    _Float16* __restrict__ latent)
{
    int id = blockIdx.x;
    int P = (id & 7) + 8 * ((id >> 3) >> 7);
    int mt = (id >> 3) & 127;
    int e = P >> 4, nt = P & 15;

    int n_e = counts[e];
    if (mt * BM >= n_e) return;
    int slot0 = offsets[e] + mt * BM;
    int mrem = n_e - mt * BM;

    __shared__ _Float16 As[NBUF][BM * BK];
    __shared__ _Float16 Bs[NBUF][BN * BK];
    __shared__ int s_tok[BM];

    int tid = threadIdx.x;
    if (tid < BM) s_tok[tid] = (tid < mrem) ? order[slot0 + tid] : 0;  // clamp: garbage rows dropped at store
    __syncthreads();

    int wave = tid >> 6, lane = tid & 63;
    int wm = wave >> 1, wn = wave & 1;

    int r_lo = wave * 16 + (lane >> 2);          // row 0..63
    int sc = lane & 3;
    int c = (sc - (r_lo >> 1)) & 3;
    const _Float16* Be = encT + (size_t)e * D_IN * EXPERT_DIM + (size_t)(nt * BN) * D_IN;
    const _Float16* pa0 = act_h + (size_t)s_tok[r_lo] * D_IN + c * 8;
    const _Float16* pa1 = act_h + (size_t)s_tok[r_lo + 64] * D_IN + c * 8;
    const _Float16* pb0 = Be + (size_t)r_lo * D_IN + c * 8;
    const _Float16* pb1 = Be + (size_t)(r_lo + 64) * D_IN + c * 8;

    int frag_off = ((((lane >> 4) + ((lane & 15) >> 1)) & 3) * 8);
    int mrow = lane & 15;

    floatx4 acc[4][4];
#pragma unroll
    for (int i = 0; i < 4; ++i)
#pragma unroll
        for (int j = 0; j < 4; ++j) acc[i][j] = (floatx4){0.f, 0.f, 0.f, 0.f};

#define ENC_ISSUE(kk, buf)                                            \
    do {                                                              \
        int k0_ = (kk) * BK;                                          \
        glds16(pa0 + k0_, &As[buf][(wave * 64) * 8]);                 \
        glds16(pa1 + k0_, &As[buf][(256 + wave * 64) * 8]);           \
        glds16(pb0 + k0_, &Bs[buf][(wave * 64) * 8]);                 \
        glds16(pb1 + k0_, &Bs[buf][(256 + wave * 64) * 8]);           \
    } while (0)

    const int NT = D_IN / BK;   // 24
    ENC_ISSUE(0, 0);
    ENC_ISSUE(1, 1);
    int buf = 0, nxt = 2;
#pragma unroll 1
    for (int k = 0; k < NT; ++k) {
        if (k + 2 < NT) {
            ENC_ISSUE(k + 2, nxt);
            __builtin_amdgcn_s_waitcnt(WAIT_VM8);   // tile k landed; k+1,k+2 in flight
        } else if (k + 1 < NT) {
            __builtin_amdgcn_s_waitcnt(WAIT_VM4);
        } else {
            __builtin_amdgcn_s_waitcnt(WAIT_VM0);
        }
        __builtin_amdgcn_s_barrier();
        half8 af[4], bf[4];
#pragma unroll
        for (int i = 0; i < 4; ++i) af[i] = *(const half8*)&As[buf][(wm * 64 + i * 16 + mrow) * BK + frag_off];
#pragma unroll
        for (int i = 0; i < 4; ++i) bf[i] = *(const half8*)&Bs[buf][(wn * 64 + i * 16 + mrow) * BK + frag_off];
#pragma unroll
        for (int i = 0; i < 4; ++i)
#pragma unroll
            for (int j = 0; j < 4; ++j)
                acc[i][j] = __builtin_amdgcn_mfma_f32_16x16x32_f16(af[i], bf[j], acc[i][j], 0, 0, 0);
        __builtin_amdgcn_s_barrier();   // all waves done reading buf before its reuse as k+3's target
        buf = (buf == NBUF - 1) ? 0 : buf + 1;
        nxt = (nxt == NBUF - 1) ? 0 : nxt + 1;
    }
#undef ENC_ISSUE

    int crow_base = wm * 64 + (lane >> 4) * 4;
    int ccol_base = nt * BN + wn * 64 + (lane & 15);
#pragma unroll
    for (int i = 0; i < 4; ++i) {
#pragma unroll
        for (int j = 0; j < 4; ++j) {
#pragma unroll
            for (int r = 0; r < 4; ++r) {
                int row = crow_base + i * 16 + r;
                if (row < mrem) {
                    float v = acc[i][j][r];
                    v = v > 0.f ? v : 0.f;
                    latent[(size_t)(slot0 + row) * EXPERT_DIM + ccol_base + j * 16] = (_Float16)v;
                }
            }
        }
    }
}

// ---------------- Decode GEMM (triple-buffered, depth-2 prefetch, XCD swizzle) ----------------
// 1D grid 6144: xcd = id&7, r = id>>3 (768); group_within = r/128 (6), mt = r&127;
// P = xcd + 8*group_within in [0,48): e = P/6, nt = P%6.
__global__ __launch_bounds__(256) void decode_kernel(const _Float16* __restrict__ latent,
    const _Float16* __restrict__ decT, const int* __restrict__ order,
    const int* __restrict__ counts, const int* __restrict__ offsets,
    const float* __restrict__ prob, const float* __restrict__ pre_b,
    float* __restrict__ out)
{
    int id = blockIdx.x;
    int P = (id & 7) + 8 * ((id >> 3) >> 7);
    int mt = (id >> 3) & 127;
    int e = P / 6, nt = P - e * 6;

    int n_e = counts[e];
    if (mt * BM >= n_e) return;
    int slot0 = offsets[e] + mt * BM;
    int mrem = n_e - mt * BM;

    __shared__ _Float16 As[NBUF][BM * BK];
    __shared__ _Float16 Bs[NBUF][BN * BK];
    __shared__ int s_tok[BM];
    __shared__ float s_p[BM];

    int tid = threadIdx.x;
    if (tid < BM) {
        int tok = (tid < mrem) ? order[slot0 + tid] : 0;
        s_tok[tid] = tok;
        s_p[tid] = prob[tok];
    }
    __syncthreads();

    const _Float16* Ae = latent + (size_t)slot0 * EXPERT_DIM;   // latent padded by BM rows
    const _Float16* Be = decT + (size_t)e * EXPERT_DIM * D_IN + (size_t)(nt * BN) * EXPERT_DIM;

    int wave = tid >> 6, lane = tid & 63;
    int wm = wave >> 1, wn = wave & 1;

    int r_lo = wave * 16 + (lane >> 2);
    int sc = lane & 3;
    int c = (sc - (r_lo >> 1)) & 3;
    const _Float16* pa0 = Ae + (size_t)r_lo * EXPERT_DIM + c * 8;
    const _Float16* pa1 = Ae + (size_t)(r_lo + 64) * EXPERT_DIM + c * 8;
    const _Float16* pb0 = Be + (size_t)r_lo * EXPERT_DIM + c * 8;
    const _Float16* pb1 = Be + (size_t)(r_lo + 64) * EXPERT_DIM + c * 8;

    int frag_off = ((((lane >> 4) + ((lane & 15) >> 1)) & 3) * 8);
    int mrow = lane & 15;

    floatx4 acc[4][4];
#pragma unroll
    for (int i = 0; i < 4; ++i)
#pragma unroll
        for (int j = 0; j < 4; ++j) acc[i][j] = (floatx4){0.f, 0.f, 0.f, 0.f};

#define DEC_ISSUE(kk, buf)                                            \
    do {                                                              \
        int k0_ = (kk) * BK;                                          \
        glds16(pa0 + k0_, &As[buf][(wave * 64) * 8]);                 \
        glds16(pa1 + k0_, &As[buf][(256 + wave * 64) * 8]);           \
        glds16(pb0 + k0_, &Bs[buf][(wave * 64) * 8]);                 \
        glds16(pb1 + k0_, &Bs[buf][(256 + wave * 64) * 8]);           \
    } while (0)

    const int NT = EXPERT_DIM / BK;   // 64
    DEC_ISSUE(0, 0);
    DEC_ISSUE(1, 1);
    int buf = 0, nxt = 2;
#pragma unroll 1
    for (int k = 0; k < NT; ++k) {
        if (k + 2 < NT) {
            DEC_ISSUE(k + 2, nxt);
            __builtin_amdgcn_s_waitcnt(WAIT_VM8);
        } else if (k + 1 < NT) {
            __builtin_amdgcn_s_waitcnt(WAIT_VM4);
        } else {
            __builtin_amdgcn_s_waitcnt(WAIT_VM0);
        }
        __builtin_amdgcn_s_barrier();
        half8 af[4], bf[4];
#pragma unroll
        for (int i = 0; i < 4; ++i) af[i] = *(const half8*)&As[buf][(wm * 64 + i * 16 + mrow) * BK + frag_off];
#pragma unroll
        for (int i = 0; i < 4; ++i) bf[i] = *(const half8*)&Bs[buf][(wn * 64 + i * 16 + mrow) * BK + frag_off];
#pragma unroll
        for (int i = 0; i < 4; ++i)
#pragma unroll
            for (int j = 0; j < 4; ++j)
                acc[i][j] = __builtin_amdgcn_mfma_f32_16x16x32_f16(af[i], bf[j], acc[i][j], 0, 0, 0);
        __builtin_amdgcn_s_barrier();
        buf = (buf == NBUF - 1) ? 0 : buf + 1;
        nxt = (nxt == NBUF - 1) ? 0 : nxt + 1;
    }
#undef DEC_ISSUE

    int crow_base = wm * 64 + (lane >> 4) * 4;
    int ccol_base = nt * BN + wn * 64 + (lane & 15);
#pragma unroll
    for (int i = 0; i < 4; ++i) {
#pragma unroll
        for (int j = 0; j < 4; ++j) {
            int col = ccol_base + j * 16;
            float pb = pre_b[col];
#pragma unroll
            for (int r = 0; r < 4; ++r) {
                int row = crow_base + i * 16 + r;
                if (row < mrem) {
                    out[(size_t)s_tok[row] * D_IN + col] = s_p[row] * acc[i][j][r] + pb;
                }
            }
        }
    }
}

extern "C" void kernel_launch(void* const* d_in, const int* in_sizes, int n_in,
                              void* d_out, int out_size, void* d_ws, size_t ws_size,
                              hipStream_t stream)
{
    const float* act      = (const float*)d_in[0];
    const float* pre_b    = (const float*)d_in[1];
    const float* enc      = (const float*)d_in[2];
    const float* dec      = (const float*)d_in[3];
    const float* router_b = (const float*)d_in[4];
    const float* router   = (const float*)d_in[5];
    float* out = (float*)d_out;

    char* w = (char*)d_ws;
    int* counts  = (int*)w;  w += 256;
    int* offsets = (int*)w;  w += 256;
    int* hist    = (int*)w;  w += ROUTER_BLOCKS * N_EXPERTS * 4;
    int* eidx    = (int*)w;  w += N_TOKENS * 4;
    int* lpos    = (int*)w;  w += N_TOKENS * 4;
    int* order   = (int*)w;  w += N_TOKENS * 4;
    float* prob  = (float*)w; w += N_TOKENS * 4;
    _Float16* act_h  = (_Float16*)w; w += (size_t)N_TOKENS * D_IN * 2;
    _Float16* encT   = (_Float16*)w; w += (size_t)N_EXPERTS * D_IN * EXPERT_DIM * 2;
    _Float16* decT   = (_Float16*)w; w += (size_t)N_EXPERTS * D_IN * EXPERT_DIM * 2;
    _Float16* latent = (_Float16*)w; w += (size_t)(N_TOKENS + BM) * EXPERT_DIM * 2;

    router_kernel<<<ROUTER_BLOCKS, 256, 0, stream>>>(act, router_b, router, prob, lpos, eidx, hist);
    scan_kernel<<<1, 256, 0, stream>>>(hist, counts, offsets);
    order_kernel<<<N_TOKENS / 256, 256, 0, stream>>>(eidx, lpos, hist, order);

    convert_act<<<N_TOKENS * D_IN / (256 * 8), 256, 0, stream>>>(act, act_h);
    transpose_to_half<<<dim3(EXPERT_DIM / 64, D_IN / 64, N_EXPERTS), 256, 0, stream>>>(enc, encT, D_IN, EXPERT_DIM);
    transpose_to_half<<<dim3(D_IN / 64, EXPERT_DIM / 64, N_EXPERTS), 256, 0, stream>>>(dec, decT, EXPERT_DIM, D_IN);

    encode_kernel<<<16384, 256, 0, stream>>>(act_h, encT, order, counts, offsets, latent);
    decode_kernel<<<6144, 256, 0, stream>>>(latent, decT, order, counts, offsets, prob, pre_b, out);
}

// Round 2
// 389.419 us; speedup vs baseline: 1.0270x; 1.0270x over previous
//
#include <hip/hip_runtime.h>
#include <hip/hip_bf16.h>
#include <hip/hip_fp16.h>

#define N_TOKENS 16384
#define D_IN 768
#define N_EXPERTS 8
#define EXPERT_DIM 2048

#define ROUTER_BLOCKS 256
#define TOK_PER_BLOCK 64

typedef _Float16 half8 __attribute__((ext_vector_type(8)));
typedef float floatx4 __attribute__((ext_vector_type(4)));

#define BM 128
#define BN 128
#define BK 32
#define NBUF 3
// LDS tiles: UNPADDED 128x32 halves (64B rows), triple-buffered (prefetch depth 2).
// Swizzle: 16B chunk c of row r stored at chunk (c + (r>>1)) & 3 -> frag
// ds_read_b128 conflict-free (verified: SQ_LDS_BANK_CONFLICT == 0 in r3/r4).

// s_waitcnt imm (gfx9): vmcnt[3:0] | expcnt<<4 | lgkmcnt<<8 | vmcnt[5:4]<<14
#define WAIT_VM8 0xF78   // vmcnt(8)  : tiles k+1,k+2 in flight, tile k landed
#define WAIT_VM4 0xF74   // vmcnt(4)
#define WAIT_VM0 0xF70   // vmcnt(0)

__device__ __forceinline__ void glds16(const _Float16* g, _Float16* l) {
    __builtin_amdgcn_global_load_lds(
        (const __attribute__((address_space(1))) unsigned int*)g,
        (__attribute__((address_space(3))) unsigned int*)l, 16, 0, 0);
}

// ---------------- act fp32 -> f16 (one-time) ----------------
__global__ __launch_bounds__(256) void convert_act(const float* __restrict__ act,
    _Float16* __restrict__ act_h)
{
    size_t i = ((size_t)blockIdx.x * 256 + threadIdx.x) * 8;
    float4 v0 = *(const float4*)(act + i);
    float4 v1 = *(const float4*)(act + i + 4);
    half8 h;
    h[0] = (_Float16)v0.x; h[1] = (_Float16)v0.y; h[2] = (_Float16)v0.z; h[3] = (_Float16)v0.w;
    h[4] = (_Float16)v1.x; h[5] = (_Float16)v1.y; h[6] = (_Float16)v1.z; h[7] = (_Float16)v1.w;
    *(half8*)(act_h + i) = h;
}

// ---------------- Phase 1: router (fp32: argmax is a decision, keep exact) ----------------
__global__ __launch_bounds__(256) void router_kernel(const float* __restrict__ act,
    const float* __restrict__ router_b, const float* __restrict__ router,
    float* __restrict__ prob, int* __restrict__ localpos, int* __restrict__ eidx,
    int* __restrict__ hist)
{
    __shared__ int h[N_EXPERTS];
    if (threadIdx.x < N_EXPERTS) h[threadIdx.x] = 0;
    __syncthreads();

    int wave = threadIdx.x >> 6, lane = threadIdx.x & 63;
#pragma unroll 1
    for (int it = 0; it < 16; ++it) {
        int t = blockIdx.x * TOK_PER_BLOCK + wave * 16 + it;
        float acc[8];
#pragma unroll
        for (int e = 0; e < 8; ++e) acc[e] = 0.f;
        const float* arow = act + (size_t)t * D_IN;
#pragma unroll
        for (int i0 = 0; i0 < D_IN; i0 += 64) {
            int i = i0 + lane;
            float a = arow[i] - router_b[i];
            const float* r = router + i * 8;
#pragma unroll
            for (int e = 0; e < 8; ++e) acc[e] += a * r[e];
        }
#pragma unroll
        for (int s = 32; s > 0; s >>= 1) {
#pragma unroll
            for (int e = 0; e < 8; ++e) acc[e] += __shfl_down(acc[e], s, 64);
        }
        if (lane == 0) {
            float m = acc[0]; int ai = 0;
#pragma unroll
            for (int e = 1; e < 8; ++e) if (acc[e] > m) { m = acc[e]; ai = e; }
            float s = 0.f;
#pragma unroll
            for (int e = 0; e < 8; ++e) s += __expf(acc[e] - m);
            prob[t] = 1.0f / s;
            eidx[t] = ai;
            localpos[t] = atomicAdd(&h[ai], 1);
        }
    }
    __syncthreads();
    if (threadIdx.x < N_EXPERTS) hist[blockIdx.x * N_EXPERTS + threadIdx.x] = h[threadIdx.x];
}

// ---------------- Phase 2: scan ----------------
__global__ __launch_bounds__(256) void scan_kernel(int* __restrict__ hist,
    int* __restrict__ counts, int* __restrict__ offsets)
{
    __shared__ int sh[ROUTER_BLOCKS * N_EXPERTS];
    __shared__ int tot[N_EXPERTS], off[N_EXPERTS];
    int tid = threadIdx.x;
    *(int4*)&sh[tid * 8]     = *(const int4*)&hist[tid * 8];
    *(int4*)&sh[tid * 8 + 4] = *(const int4*)&hist[tid * 8 + 4];
    __syncthreads();
    if (tid < N_EXPERTS) {
        int run = 0;
        for (int b = 0; b < ROUTER_BLOCKS; ++b) {
            int v = sh[b * 8 + tid];
            sh[b * 8 + tid] = run;
            run += v;
        }
        tot[tid] = run;
    }
    __syncthreads();
    if (tid == 0) {
        int run = 0;
        for (int e = 0; e < N_EXPERTS; ++e) {
            off[e] = run; offsets[e] = run; counts[e] = tot[e]; run += tot[e];
        }
    }
    __syncthreads();
    int4 a = *(const int4*)&sh[tid * 8];
    int4 b = *(const int4*)&sh[tid * 8 + 4];
    a.x += off[0]; a.y += off[1]; a.z += off[2]; a.w += off[3];
    b.x += off[4]; b.y += off[5]; b.z += off[6]; b.w += off[7];
    *(int4*)&hist[tid * 8]     = a;
    *(int4*)&hist[tid * 8 + 4] = b;
}

// ---------------- Phase 3: scatter ----------------
__global__ __launch_bounds__(256) void order_kernel(const int* __restrict__ eidx,
    const int* __restrict__ localpos, const int* __restrict__ hist,
    int* __restrict__ order)
{
    int t = blockIdx.x * 256 + threadIdx.x;
    int base = hist[(t >> 6) * N_EXPERTS + eidx[t]];
    order[base + localpos[t]] = t;
}

// ---------------- Weight transpose fp32 [E][K][Nc] -> f16 [E][Nc][K] ----------------
__global__ __launch_bounds__(256) void transpose_to_half(const float* __restrict__ W,
    _Float16* __restrict__ WT, int K, int Nc)
{
    __shared__ _Float16 tile[64][72];
    size_t esz = (size_t)K * Nc;
    const float* We = W + (size_t)blockIdx.z * esz;
    _Float16* WTe = WT + (size_t)blockIdx.z * esz;
    int n0 = blockIdx.x * 64, k0 = blockIdx.y * 64;
    int tr = threadIdx.x >> 4;
    int tc = threadIdx.x & 15;
#pragma unroll
    for (int rr = 0; rr < 64; rr += 16) {
        int k = k0 + rr + tr;
        float4 v = *(const float4*)(We + (size_t)k * Nc + n0 + tc * 4);
        tile[tc * 4 + 0][rr + tr] = (_Float16)v.x;
        tile[tc * 4 + 1][rr + tr] = (_Float16)v.y;
        tile[tc * 4 + 2][rr + tr] = (_Float16)v.z;
        tile[tc * 4 + 3][rr + tr] = (_Float16)v.w;
    }
    __syncthreads();
#pragma unroll
    for (int p = 0; p < 2; ++p) {
        int id = threadIdx.x + p * 256;
        int r = id >> 3, ch = id & 7;
        half8 v = *(const half8*)&tile[r][ch * 8];
        *(half8*)(WTe + (size_t)(n0 + r) * K + k0 + ch * 8) = v;
    }
}

// ---------------- Encode GEMM (triple-buffered, depth-2 prefetch, expert->XCD swizzle) ----------------
// 1D grid 16384: e = id&7 (expert == XCD), j = id>>3 in [0,2048): nt = j&15, mt = j>>4.
// nt varies fastest: co-resident ~96 blocks/XCD = 6 mt-groups x all 16 nt ->
// encT[e] (3.1 MB) L2-resident for the whole expert; act_h rows fetched ~once
// (concurrent nt-blocks of one mt miss-merge on the same A tile).
__global__ __launch_bounds__(256) void encode_kernel(const _Float16* __restrict__ act_h,
    const _Float16* __restrict__ encT, const int* __restrict__ order,
    const int* __restrict__ counts, const int* __restrict__ offsets,
    _Float16* __restrict__ latent)
{
    int id = blockIdx.x;
    int e = id & 7;
    int j = id >> 3;          // [0, 2048)
    int nt = j & 15;
    int mt = j >> 4;          // [0, 128)

    int n_e = counts[e];
    if (mt * BM >= n_e) return;
    int slot0 = offsets[e] + mt * BM;
    int mrem = n_e - mt * BM;

    __shared__ _Float16 As[NBUF][BM * BK];
    __shared__ _Float16 Bs[NBUF][BN * BK];
    __shared__ int s_tok[BM];

    int tid = threadIdx.x;
    if (tid < BM) s_tok[tid] = (tid < mrem) ? order[slot0 + tid] : 0;  // clamp: garbage rows dropped at store
    __syncthreads();

    int wave = tid >> 6, lane = tid & 63;
    int wm = wave >> 1, wn = wave & 1;

    int r_lo = wave * 16 + (lane >> 2);          // row 0..63
    int sc = lane & 3;
    int c = (sc - (r_lo >> 1)) & 3;
    const _Float16* Be = encT + (size_t)e * D_IN * EXPERT_DIM + (size_t)(nt * BN) * D_IN;
    const _Float16* pa0 = act_h + (size_t)s_tok[r_lo] * D_IN + c * 8;
    const _Float16* pa1 = act_h + (size_t)s_tok[r_lo + 64] * D_IN + c * 8;
    const _Float16* pb0 = Be + (size_t)r_lo * D_IN + c * 8;
    const _Float16* pb1 = Be + (size_t)(r_lo + 64) * D_IN + c * 8;

    int frag_off = ((((lane >> 4) + ((lane & 15) >> 1)) & 3) * 8);
    int mrow = lane & 15;

    floatx4 acc[4][4];
#pragma unroll
    for (int i = 0; i < 4; ++i)
#pragma unroll
        for (int j2 = 0; j2 < 4; ++j2) acc[i][j2] = (floatx4){0.f, 0.f, 0.f, 0.f};

#define ENC_ISSUE(kk, buf)                                            \
    do {                                                              \
        int k0_ = (kk) * BK;                                          \
        glds16(pa0 + k0_, &As[buf][(wave * 64) * 8]);                 \
        glds16(pa1 + k0_, &As[buf][(256 + wave * 64) * 8]);           \
        glds16(pb0 + k0_, &Bs[buf][(wave * 64) * 8]);                 \
        glds16(pb1 + k0_, &Bs[buf][(256 + wave * 64) * 8]);           \
    } while (0)

    const int NT = D_IN / BK;   // 24
    ENC_ISSUE(0, 0);
    ENC_ISSUE(1, 1);
    int buf = 0, nxt = 2;
#pragma unroll 1
    for (int k = 0; k < NT; ++k) {
        if (k + 2 < NT) {
            ENC_ISSUE(k + 2, nxt);
            __builtin_amdgcn_s_waitcnt(WAIT_VM8);   // tile k landed; k+1,k+2 in flight
        } else if (k + 1 < NT) {
            __builtin_amdgcn_s_waitcnt(WAIT_VM4);
        } else {
            __builtin_amdgcn_s_waitcnt(WAIT_VM0);
        }
        __builtin_amdgcn_s_barrier();
        half8 af[4], bf[4];
#pragma unroll
        for (int i = 0; i < 4; ++i) af[i] = *(const half8*)&As[buf][(wm * 64 + i * 16 + mrow) * BK + frag_off];
#pragma unroll
        for (int i = 0; i < 4; ++i) bf[i] = *(const half8*)&Bs[buf][(wn * 64 + i * 16 + mrow) * BK + frag_off];
#pragma unroll
        for (int i = 0; i < 4; ++i)
#pragma unroll
            for (int j2 = 0; j2 < 4; ++j2)
                acc[i][j2] = __builtin_amdgcn_mfma_f32_16x16x32_f16(af[i], bf[j2], acc[i][j2], 0, 0, 0);
        __builtin_amdgcn_s_barrier();   // all waves done reading buf before its reuse as k+3's target
        buf = (buf == NBUF - 1) ? 0 : buf + 1;
        nxt = (nxt == NBUF - 1) ? 0 : nxt + 1;
    }
#undef ENC_ISSUE

    int crow_base = wm * 64 + (lane >> 4) * 4;
    int ccol_base = nt * BN + wn * 64 + (lane & 15);
#pragma unroll
    for (int i = 0; i < 4; ++i) {
#pragma unroll
        for (int j2 = 0; j2 < 4; ++j2) {
#pragma unroll
            for (int r = 0; r < 4; ++r) {
                int row = crow_base + i * 16 + r;
                if (row < mrem) {
                    float v = acc[i][j2][r];
                    v = v > 0.f ? v : 0.f;
                    latent[(size_t)(slot0 + row) * EXPERT_DIM + ccol_base + j2 * 16] = (_Float16)v;
                }
            }
        }
    }
}

// ---------------- Decode GEMM (triple-buffered, depth-2 prefetch, expert->XCD swizzle) ----------------
// 1D grid 6144: e = id&7 (expert == XCD), j = id>>3 in [0,768): nt = j%6, mt = j/6.
// The whole expert (~96 active blocks = 16 mt x 6 nt) is co-resident on one XCD:
// all 6 nt-blocks of one mt read the same latent tile concurrently (miss-merge,
// latent fetched ~1x instead of ~3x) and decT[e] (3 MB) stays L2-resident.
__global__ __launch_bounds__(256) void decode_kernel(const _Float16* __restrict__ latent,
    const _Float16* __restrict__ decT, const int* __restrict__ order,
    const int* __restrict__ counts, const int* __restrict__ offsets,
    const float* __restrict__ prob, const float* __restrict__ pre_b,
    float* __restrict__ out)
{
    int id = blockIdx.x;
    int e = id & 7;
    int j = id >> 3;          // [0, 768)
    int nt = j % 6;
    int mt = j / 6;           // [0, 128)

    int n_e = counts[e];
    if (mt * BM >= n_e) return;
    int slot0 = offsets[e] + mt * BM;
    int mrem = n_e - mt * BM;

    __shared__ _Float16 As[NBUF][BM * BK];
    __shared__ _Float16 Bs[NBUF][BN * BK];
    __shared__ int s_tok[BM];
    __shared__ float s_p[BM];

    int tid = threadIdx.x;
    if (tid < BM) {
        int tok = (tid < mrem) ? order[slot0 + tid] : 0;
        s_tok[tid] = tok;
        s_p[tid] = prob[tok];
    }
    __syncthreads();

    const _Float16* Ae = latent + (size_t)slot0 * EXPERT_DIM;   // latent padded by BM rows
    const _Float16* Be = decT + (size_t)e * EXPERT_DIM * D_IN + (size_t)(nt * BN) * EXPERT_DIM;

    int wave = tid >> 6, lane = tid & 63;
    int wm = wave >> 1, wn = wave & 1;

    int r_lo = wave * 16 + (lane >> 2);
    int sc = lane & 3;
    int c = (sc - (r_lo >> 1)) & 3;
    const _Float16* pa0 = Ae + (size_t)r_lo * EXPERT_DIM + c * 8;
    const _Float16* pa1 = Ae + (size_t)(r_lo + 64) * EXPERT_DIM + c * 8;
    const _Float16* pb0 = Be + (size_t)r_lo * EXPERT_DIM + c * 8;
    const _Float16* pb1 = Be + (size_t)(r_lo + 64) * EXPERT_DIM + c * 8;

    int frag_off = ((((lane >> 4) + ((lane & 15) >> 1)) & 3) * 8);
    int mrow = lane & 15;

    floatx4 acc[4][4];
#pragma unroll
    for (int i = 0; i < 4; ++i)
#pragma unroll
        for (int j2 = 0; j2 < 4; ++j2) acc[i][j2] = (floatx4){0.f, 0.f, 0.f, 0.f};

#define DEC_ISSUE(kk, buf)                                            \
    do {                                                              \
        int k0_ = (kk) * BK;                                          \
        glds16(pa0 + k0_, &As[buf][(wave * 64) * 8]);                 \
        glds16(pa1 + k0_, &As[buf][(256 + wave * 64) * 8]);           \
        glds16(pb0 + k0_, &Bs[buf][(wave * 64) * 8]);                 \
        glds16(pb1 + k0_, &Bs[buf][(256 + wave * 64) * 8]);           \
    } while (0)

    const int NT = EXPERT_DIM / BK;   // 64
    DEC_ISSUE(0, 0);
    DEC_ISSUE(1, 1);
    int buf = 0, nxt = 2;
#pragma unroll 1
    for (int k = 0; k < NT; ++k) {
        if (k + 2 < NT) {
            DEC_ISSUE(k + 2, nxt);
            __builtin_amdgcn_s_waitcnt(WAIT_VM8);
        } else if (k + 1 < NT) {
            __builtin_amdgcn_s_waitcnt(WAIT_VM4);
        } else {
            __builtin_amdgcn_s_waitcnt(WAIT_VM0);
        }
        __builtin_amdgcn_s_barrier();
        half8 af[4], bf[4];
#pragma unroll
        for (int i = 0; i < 4; ++i) af[i] = *(const half8*)&As[buf][(wm * 64 + i * 16 + mrow) * BK + frag_off];
#pragma unroll
        for (int i = 0; i < 4; ++i) bf[i] = *(const half8*)&Bs[buf][(wn * 64 + i * 16 + mrow) * BK + frag_off];
#pragma unroll
        for (int i = 0; i < 4; ++i)
#pragma unroll
            for (int j2 = 0; j2 < 4; ++j2)
                acc[i][j2] = __builtin_amdgcn_mfma_f32_16x16x32_f16(af[i], bf[j2], acc[i][j2], 0, 0, 0);
        __builtin_amdgcn_s_barrier();
        buf = (buf == NBUF - 1) ? 0 : buf + 1;
        nxt = (nxt == NBUF - 1) ? 0 : nxt + 1;
    }
#undef DEC_ISSUE

    int crow_base = wm * 64 + (lane >> 4) * 4;
    int ccol_base = nt * BN + wn * 64 + (lane & 15);
#pragma unroll
    for (int i = 0; i < 4; ++i) {
#pragma unroll
        for (int j2 = 0; j2 < 4; ++j2) {
            int col = ccol_base + j2 * 16;
            float pb = pre_b[col];
#pragma unroll
            for (int r = 0; r < 4; ++r) {
                int row = crow_base + i * 16 + r;
                if (row < mrem) {
                    out[(size_t)s_tok[row] * D_IN + col] = s_p[row] * acc[i][j2][r] + pb;
                }
            }
        }
    }
}

extern "C" void kernel_launch(void* const* d_in, const int* in_sizes, int n_in,
                              void* d_out, int out_size, void* d_ws, size_t ws_size,
                              hipStream_t stream)
{
    const float* act      = (const float*)d_in[0];
    const float* pre_b    = (const float*)d_in[1];
    const float* enc      = (const float*)d_in[2];
    const float* dec      = (const float*)d_in[3];
    const float* router_b = (const float*)d_in[4];
    const float* router   = (const float*)d_in[5];
    float* out = (float*)d_out;

    char* w = (char*)d_ws;
    int* counts  = (int*)w;  w += 256;
    int* offsets = (int*)w;  w += 256;
    int* hist    = (int*)w;  w += ROUTER_BLOCKS * N_EXPERTS * 4;
    int* eidx    = (int*)w;  w += N_TOKENS * 4;
    int* lpos    = (int*)w;  w += N_TOKENS * 4;
    int* order   = (int*)w;  w += N_TOKENS * 4;
    float* prob  = (float*)w; w += N_TOKENS * 4;
    _Float16* act_h  = (_Float16*)w; w += (size_t)N_TOKENS * D_IN * 2;
    _Float16* encT   = (_Float16*)w; w += (size_t)N_EXPERTS * D_IN * EXPERT_DIM * 2;
    _Float16* decT   = (_Float16*)w; w += (size_t)N_EXPERTS * D_IN * EXPERT_DIM * 2;
    _Float16* latent = (_Float16*)w; w += (size_t)(N_TOKENS + BM) * EXPERT_DIM * 2;

    router_kernel<<<ROUTER_BLOCKS, 256, 0, stream>>>(act, router_b, router, prob, lpos, eidx, hist);
    scan_kernel<<<1, 256, 0, stream>>>(hist, counts, offsets);
    order_kernel<<<N_TOKENS / 256, 256, 0, stream>>>(eidx, lpos, hist, order);

    convert_act<<<N_TOKENS * D_IN / (256 * 8), 256, 0, stream>>>(act, act_h);
    transpose_to_half<<<dim3(EXPERT_DIM / 64, D_IN / 64, N_EXPERTS), 256, 0, stream>>>(enc, encT, D_IN, EXPERT_DIM);
    transpose_to_half<<<dim3(D_IN / 64, EXPERT_DIM / 64, N_EXPERTS), 256, 0, stream>>>(dec, decT, EXPERT_DIM, D_IN);

    encode_kernel<<<16384, 256, 0, stream>>>(act_h, encT, order, counts, offsets, latent);
    decode_kernel<<<6144, 256, 0, stream>>>(latent, decT, order, counts, offsets, prob, pre_b, out);
}

// Round 4
// 384.989 us; speedup vs baseline: 1.0388x; 1.0115x over previous
//
#include <hip/hip_runtime.h>
#include <hip/hip_bf16.h>
#include <hip/hip_fp16.h>

#define N_TOKENS 16384
#define D_IN 768
#define N_EXPERTS 8
#define EXPERT_DIM 2048

#define ROUTER_BLOCKS 256
#define TOK_PER_BLOCK 64

typedef _Float16 half8 __attribute__((ext_vector_type(8)));
typedef float floatx4 __attribute__((ext_vector_type(4)));

// ---- 256x256 GEMM geometry (8 waves = 2m x 4n, per-wave 128x64 out, BK=64) ----
#define GBM 256
#define GBN 256
#define GBK 64
// LDS per buffer: A 256x64 halves (32KB) + B 256x64 (32KB); dbuf = 128KB.
// Row = 128B = 8 chunks of 16B. Swizzle: chunk c of row r at phys chunk (c+(r>>1))&7.
// ds_read_b128: 8 lanes per chunk over the wave = exact 8-access minimum -> conflict-free.
// Staging via global_load_lds (linear LDS dest = wave base + lane*16B, HW requirement);
// the swizzle is applied on the per-lane GLOBAL source chunk: c_st = (pc - (row>>1))&7.

// s_waitcnt imm (gfx9): vmcnt[3:0] | expcnt<<4 | lgkmcnt<<8 | vmcnt[5:4]<<14
#define WAIT_VM0 0xF70   // vmcnt(0)

__device__ __forceinline__ void glds16(const _Float16* g, _Float16* l) {
    __builtin_amdgcn_global_load_lds(
        (const __attribute__((address_space(1))) unsigned int*)g,
        (__attribute__((address_space(3))) unsigned int*)l, 16, 0, 0);
}

// ---------------- act fp32 -> f16 (one-time) ----------------
__global__ __launch_bounds__(256) void convert_act(const float* __restrict__ act,
    _Float16* __restrict__ act_h)
{
    size_t i = ((size_t)blockIdx.x * 256 + threadIdx.x) * 8;
    float4 v0 = *(const float4*)(act + i);
    float4 v1 = *(const float4*)(act + i + 4);
    half8 h;
    h[0] = (_Float16)v0.x; h[1] = (_Float16)v0.y; h[2] = (_Float16)v0.z; h[3] = (_Float16)v0.w;
    h[4] = (_Float16)v1.x; h[5] = (_Float16)v1.y; h[6] = (_Float16)v1.z; h[7] = (_Float16)v1.w;
    *(half8*)(act_h + i) = h;
}

// ---------------- Phase 1: router ----------------
__global__ __launch_bounds__(256) void router_kernel(const float* __restrict__ act,
    const float* __restrict__ router_b, const float* __restrict__ router,
    float* __restrict__ prob, int* __restrict__ localpos, int* __restrict__ eidx,
    int* __restrict__ hist)
{
    __shared__ int h[N_EXPERTS];
    if (threadIdx.x < N_EXPERTS) h[threadIdx.x] = 0;
    __syncthreads();

    int wave = threadIdx.x >> 6, lane = threadIdx.x & 63;
#pragma unroll 1
    for (int it = 0; it < 16; ++it) {
        int t = blockIdx.x * TOK_PER_BLOCK + wave * 16 + it;
        float acc[8];
#pragma unroll
        for (int e = 0; e < 8; ++e) acc[e] = 0.f;
        const float* arow = act + (size_t)t * D_IN;
#pragma unroll
        for (int i0 = 0; i0 < D_IN; i0 += 64) {
            int i = i0 + lane;
            float a = arow[i] - router_b[i];
            const float* r = router + i * 8;
#pragma unroll
            for (int e = 0; e < 8; ++e) acc[e] += a * r[e];
        }
#pragma unroll
        for (int s = 32; s > 0; s >>= 1) {
#pragma unroll
            for (int e = 0; e < 8; ++e) acc[e] += __shfl_down(acc[e], s, 64);
        }
        if (lane == 0) {
            float m = acc[0]; int ai = 0;
#pragma unroll
            for (int e = 1; e < 8; ++e) if (acc[e] > m) { m = acc[e]; ai = e; }
            float s = 0.f;
#pragma unroll
            for (int e = 0; e < 8; ++e) s += __expf(acc[e] - m);
            prob[t] = 1.0f / s;
            eidx[t] = ai;
            localpos[t] = atomicAdd(&h[ai], 1);
        }
    }
    __syncthreads();
    if (threadIdx.x < N_EXPERTS) hist[blockIdx.x * N_EXPERTS + threadIdx.x] = h[threadIdx.x];
}

// ---------------- Phase 2: scan ----------------
__global__ __launch_bounds__(256) void scan_kernel(int* __restrict__ hist,
    int* __restrict__ counts, int* __restrict__ offsets)
{
    __shared__ int sh[ROUTER_BLOCKS * N_EXPERTS];
    __shared__ int tot[N_EXPERTS], off[N_EXPERTS];
    int tid = threadIdx.x;
    *(int4*)&sh[tid * 8]     = *(const int4*)&hist[tid * 8];
    *(int4*)&sh[tid * 8 + 4] = *(const int4*)&hist[tid * 8 + 4];
    __syncthreads();
    if (tid < N_EXPERTS) {
        int run = 0;
        for (int b = 0; b < ROUTER_BLOCKS; ++b) {
            int v = sh[b * 8 + tid];
            sh[b * 8 + tid] = run;
            run += v;
        }
        tot[tid] = run;
    }
    __syncthreads();
    if (tid == 0) {
        int run = 0;
        for (int e = 0; e < N_EXPERTS; ++e) {
            off[e] = run; offsets[e] = run; counts[e] = tot[e]; run += tot[e];
        }
    }
    __syncthreads();
    int4 a = *(const int4*)&sh[tid * 8];
    int4 b = *(const int4*)&sh[tid * 8 + 4];
    a.x += off[0]; a.y += off[1]; a.z += off[2]; a.w += off[3];
    b.x += off[4]; b.y += off[5]; b.z += off[6]; b.w += off[7];
    *(int4*)&hist[tid * 8]     = a;
    *(int4*)&hist[tid * 8 + 4] = b;
}

// ---------------- Phase 3: scatter ----------------
__global__ __launch_bounds__(256) void order_kernel(const int* __restrict__ eidx,
    const int* __restrict__ localpos, const int* __restrict__ hist,
    int* __restrict__ order)
{
    int t = blockIdx.x * 256 + threadIdx.x;
    int base = hist[(t >> 6) * N_EXPERTS + eidx[t]];
    order[base + localpos[t]] = t;
}

// ---------------- Weight transpose fp32 [E][K][Nc] -> f16 [E][Nc][K] ----------------
__global__ __launch_bounds__(256) void transpose_to_half(const float* __restrict__ W,
    _Float16* __restrict__ WT, int K, int Nc)
{
    __shared__ _Float16 tile[64][72];
    size_t esz = (size_t)K * Nc;
    const float* We = W + (size_t)blockIdx.z * esz;
    _Float16* WTe = WT + (size_t)blockIdx.z * esz;
    int n0 = blockIdx.x * 64, k0 = blockIdx.y * 64;
    int tr = threadIdx.x >> 4;
    int tc = threadIdx.x & 15;
#pragma unroll
    for (int rr = 0; rr < 64; rr += 16) {
        int k = k0 + rr + tr;
        float4 v = *(const float4*)(We + (size_t)k * Nc + n0 + tc * 4);
        tile[tc * 4 + 0][rr + tr] = (_Float16)v.x;
        tile[tc * 4 + 1][rr + tr] = (_Float16)v.y;
        tile[tc * 4 + 2][rr + tr] = (_Float16)v.z;
        tile[tc * 4 + 3][rr + tr] = (_Float16)v.w;
    }
    __syncthreads();
#pragma unroll
    for (int p = 0; p < 2; ++p) {
        int id = threadIdx.x + p * 256;
        int r = id >> 3, ch = id & 7;
        half8 v = *(const half8*)&tile[r][ch * 8];
        *(half8*)(WTe + (size_t)(n0 + r) * K + k0 + ch * 8) = v;
    }
}

// Staging: 8 glds16 per wave per K-tile. Wave w, lane: dst = region + q*4096 + w*512 + lane*8
// (row = q*64 + w*8 + (lane>>3), phys chunk = lane&7). Source chunk c_st = ((lane&7) - 4w - (lane>>4)) & 7.
#define STAGE8(bufp, k0h)                                              \
    do {                                                               \
        glds16(pa0 + (k0h), (bufp) + 0 * 4096 + st_dst);               \
        glds16(pa1 + (k0h), (bufp) + 1 * 4096 + st_dst);               \
        glds16(pa2 + (k0h), (bufp) + 2 * 4096 + st_dst);               \
        glds16(pa3 + (k0h), (bufp) + 3 * 4096 + st_dst);               \
        glds16(pb0 + (k0h), (bufp) + 16384 + 0 * 4096 + st_dst);       \
        glds16(pb1 + (k0h), (bufp) + 16384 + 1 * 4096 + st_dst);       \
        glds16(pb2 + (k0h), (bufp) + 16384 + 2 * 4096 + st_dst);       \
        glds16(pb3 + (k0h), (bufp) + 16384 + 3 * 4096 + st_dst);       \
    } while (0)

// ---------------- Encode GEMM 256x256 (dbuf BK=64, 1 barrier/K-tile, expert->XCD) ----------------
// grid 4096: e = id&7, j = id>>3: nt = j&7 (fastest), mt = j>>3 in [0,64).
__global__ __launch_bounds__(512, 2) void encode_kernel(const _Float16* __restrict__ act_h,
    const _Float16* __restrict__ encT, const int* __restrict__ order,
    const int* __restrict__ counts, const int* __restrict__ offsets,
    _Float16* __restrict__ latent)
{
    int id = blockIdx.x;
    int e = id & 7;
    int j = id >> 3;
    int nt = j & 7;
    int mt = j >> 3;

    int n_e = counts[e];
    if (mt * GBM >= n_e) return;
    int slot0 = offsets[e] + mt * GBM;
    int mrem = n_e - mt * GBM;

    __shared__ _Float16 lds[2][32768];
    __shared__ int s_tok[GBM];

    int tid = threadIdx.x;
    if (tid < GBM) s_tok[tid] = (tid < mrem) ? order[slot0 + tid] : order[slot0];
    __syncthreads();

    int w = tid >> 6, lane = tid & 63;
    int wm = w >> 2, wn = w & 3;
    int mrow = lane & 15;

    // staging addressing
    int st_dst = w * 512 + lane * 8;
    int c_st = ((lane & 7) - (w << 2) - (lane >> 4)) & 7;
    int row_st = w * 8 + (lane >> 3);
    const _Float16* Be = encT + (size_t)e * D_IN * EXPERT_DIM + (size_t)(nt * GBN) * D_IN;
    const _Float16* pa0 = act_h + (size_t)s_tok[0 * 64 + row_st] * D_IN + c_st * 8;
    const _Float16* pa1 = act_h + (size_t)s_tok[1 * 64 + row_st] * D_IN + c_st * 8;
    const _Float16* pa2 = act_h + (size_t)s_tok[2 * 64 + row_st] * D_IN + c_st * 8;
    const _Float16* pa3 = act_h + (size_t)s_tok[3 * 64 + row_st] * D_IN + c_st * 8;
    const _Float16* pb0 = Be + (size_t)(0 * 64 + row_st) * D_IN + c_st * 8;
    const _Float16* pb1 = Be + (size_t)(1 * 64 + row_st) * D_IN + c_st * 8;
    const _Float16* pb2 = Be + (size_t)(2 * 64 + row_st) * D_IN + c_st * 8;
    const _Float16* pb3 = Be + (size_t)(3 * 64 + row_st) * D_IN + c_st * 8;

    // read addressing (kk chunk: (kk*4 + (lane>>4) + (mrow>>1)) & 7; +4 mod 8 == ^4)
    int c0 = ((lane >> 4) + (mrow >> 1)) & 7;
    int aoff0 = (wm * 128 + mrow) * 64 + c0 * 8;
    int aoff1 = (wm * 128 + mrow) * 64 + (c0 ^ 4) * 8;
    int boff0 = 16384 + (wn * 64 + mrow) * 64 + c0 * 8;
    int boff1 = 16384 + (wn * 64 + mrow) * 64 + (c0 ^ 4) * 8;

    floatx4 acc[8][4];
#pragma unroll
    for (int i = 0; i < 8; ++i)
#pragma unroll
        for (int jj = 0; jj < 4; ++jj) acc[i][jj] = (floatx4){0.f, 0.f, 0.f, 0.f};

    const int T = D_IN / GBK;   // 12
    STAGE8(&lds[0][0], 0);
    __builtin_amdgcn_s_waitcnt(WAIT_VM0);
    __builtin_amdgcn_s_barrier();

#pragma unroll 1
    for (int t = 0; t < T; ++t) {
        _Float16* cur = &lds[t & 1][0];
        if (t + 1 < T) {
            _Float16* nxt = &lds[(t + 1) & 1][0];
            int k1 = (t + 1) * GBK;
            STAGE8(nxt, k1);
        }
        // kk = 0
        half8 a0[8], b0[4];
#pragma unroll
        for (int i = 0; i < 8; ++i) a0[i] = *(const half8*)&cur[aoff0 + i * 1024];
#pragma unroll
        for (int jj = 0; jj < 4; ++jj) b0[jj] = *(const half8*)&cur[boff0 + jj * 1024];
        __builtin_amdgcn_s_setprio(1);
#pragma unroll
        for (int i = 0; i < 8; ++i)
#pragma unroll
            for (int jj = 0; jj < 4; ++jj)
                acc[i][jj] = __builtin_amdgcn_mfma_f32_16x16x32_f16(a0[i], b0[jj], acc[i][jj], 0, 0, 0);
        __builtin_amdgcn_s_setprio(0);
        // kk = 1
        half8 a1[8], b1[4];
#pragma unroll
        for (int i = 0; i < 8; ++i) a1[i] = *(const half8*)&cur[aoff1 + i * 1024];
#pragma unroll
        for (int jj = 0; jj < 4; ++jj) b1[jj] = *(const half8*)&cur[boff1 + jj * 1024];
        __builtin_amdgcn_s_setprio(1);
#pragma unroll
        for (int i = 0; i < 8; ++i)
#pragma unroll
            for (int jj = 0; jj < 4; ++jj)
                acc[i][jj] = __builtin_amdgcn_mfma_f32_16x16x32_f16(a1[i], b1[jj], acc[i][jj], 0, 0, 0);
        __builtin_amdgcn_s_setprio(0);
        if (t + 1 < T) {
            __builtin_amdgcn_s_waitcnt(WAIT_VM0);   // own 8 staging loads, issued ~2500cy ago
            __builtin_amdgcn_s_barrier();
        }
    }

    // epilogue: ReLU -> latent f16
#pragma unroll
    for (int i = 0; i < 8; ++i) {
        int row0 = wm * 128 + i * 16 + (lane >> 4) * 4;
#pragma unroll
        for (int jj = 0; jj < 4; ++jj) {
            int col = nt * GBN + wn * 64 + jj * 16 + mrow;
#pragma unroll
            for (int r = 0; r < 4; ++r) {
                int row = row0 + r;
                if (row < mrem) {
                    float v = acc[i][jj][r];
                    v = v > 0.f ? v : 0.f;
                    latent[(size_t)(slot0 + row) * EXPERT_DIM + col] = (_Float16)v;
                }
            }
        }
    }
}

// ---------------- Decode GEMM 256x256 (dbuf BK=64, 1 barrier/K-tile, expert->XCD) ----------------
// grid 1536: e = id&7, j = id>>3: nt = j%3 (fastest), mt = j/3 in [0,64).
__global__ __launch_bounds__(512, 2) void decode_kernel(const _Float16* __restrict__ latent,
    const _Float16* __restrict__ decT, const int* __restrict__ order,
    const int* __restrict__ counts, const int* __restrict__ offsets,
    const float* __restrict__ prob, const float* __restrict__ pre_b,
    float* __restrict__ out)
{
    int id = blockIdx.x;
    int e = id & 7;
    int j = id >> 3;
    int nt = j % 3;
    int mt = j / 3;

    int n_e = counts[e];
    if (mt * GBM >= n_e) return;
    int slot0 = offsets[e] + mt * GBM;
    int mrem = n_e - mt * GBM;

    __shared__ _Float16 lds[2][32768];
    __shared__ int s_tok[GBM];
    __shared__ float s_p[GBM];

    int tid = threadIdx.x;
    if (tid < GBM) {
        int tok = (tid < mrem) ? order[slot0 + tid] : order[slot0];
        s_tok[tid] = tok;
        s_p[tid] = prob[tok];
    }
    __syncthreads();

    int w = tid >> 6, lane = tid & 63;
    int wm = w >> 2, wn = w & 3;
    int mrow = lane & 15;

    int st_dst = w * 512 + lane * 8;
    int c_st = ((lane & 7) - (w << 2) - (lane >> 4)) & 7;
    int row_st = w * 8 + (lane >> 3);
    const _Float16* Ae = latent + (size_t)slot0 * EXPERT_DIM;
    const _Float16* Be = decT + (size_t)e * EXPERT_DIM * D_IN + (size_t)(nt * GBN) * EXPERT_DIM;
    const _Float16* pa0 = Ae + (size_t)(0 * 64 + row_st) * EXPERT_DIM + c_st * 8;
    const _Float16* pa1 = Ae + (size_t)(1 * 64 + row_st) * EXPERT_DIM + c_st * 8;
    const _Float16* pa2 = Ae + (size_t)(2 * 64 + row_st) * EXPERT_DIM + c_st * 8;
    const _Float16* pa3 = Ae + (size_t)(3 * 64 + row_st) * EXPERT_DIM + c_st * 8;
    const _Float16* pb0 = Be + (size_t)(0 * 64 + row_st) * EXPERT_DIM + c_st * 8;
    const _Float16* pb1 = Be + (size_t)(1 * 64 + row_st) * EXPERT_DIM + c_st * 8;
    const _Float16* pb2 = Be + (size_t)(2 * 64 + row_st) * EXPERT_DIM + c_st * 8;
    const _Float16* pb3 = Be + (size_t)(3 * 64 + row_st) * EXPERT_DIM + c_st * 8;

    int c0 = ((lane >> 4) + (mrow >> 1)) & 7;
    int aoff0 = (wm * 128 + mrow) * 64 + c0 * 8;
    int aoff1 = (wm * 128 + mrow) * 64 + (c0 ^ 4) * 8;
    int boff0 = 16384 + (wn * 64 + mrow) * 64 + c0 * 8;
    int boff1 = 16384 + (wn * 64 + mrow) * 64 + (c0 ^ 4) * 8;

    floatx4 acc[8][4];
#pragma unroll
    for (int i = 0; i < 8; ++i)
#pragma unroll
        for (int jj = 0; jj < 4; ++jj) acc[i][jj] = (floatx4){0.f, 0.f, 0.f, 0.f};

    const int T = EXPERT_DIM / GBK;   // 32
    STAGE8(&lds[0][0], 0);
    __builtin_amdgcn_s_waitcnt(WAIT_VM0);
    __builtin_amdgcn_s_barrier();

#pragma unroll 1
    for (int t = 0; t < T; ++t) {
        _Float16* cur = &lds[t & 1][0];
        if (t + 1 < T) {
            _Float16* nxt = &lds[(t + 1) & 1][0];
            int k1 = (t + 1) * GBK;
            STAGE8(nxt, k1);
        }
        half8 a0[8], b0[4];
#pragma unroll
        for (int i = 0; i < 8; ++i) a0[i] = *(const half8*)&cur[aoff0 + i * 1024];
#pragma unroll
        for (int jj = 0; jj < 4; ++jj) b0[jj] = *(const half8*)&cur[boff0 + jj * 1024];
        __builtin_amdgcn_s_setprio(1);
#pragma unroll
        for (int i = 0; i < 8; ++i)
#pragma unroll
            for (int jj = 0; jj < 4; ++jj)
                acc[i][jj] = __builtin_amdgcn_mfma_f32_16x16x32_f16(a0[i], b0[jj], acc[i][jj], 0, 0, 0);
        __builtin_amdgcn_s_setprio(0);
        half8 a1[8], b1[4];
#pragma unroll
        for (int i = 0; i < 8; ++i) a1[i] = *(const half8*)&cur[aoff1 + i * 1024];
#pragma unroll
        for (int jj = 0; jj < 4; ++jj) b1[jj] = *(const half8*)&cur[boff1 + jj * 1024];
        __builtin_amdgcn_s_setprio(1);
#pragma unroll
        for (int i = 0; i < 8; ++i)
#pragma unroll
            for (int jj = 0; jj < 4; ++jj)
                acc[i][jj] = __builtin_amdgcn_mfma_f32_16x16x32_f16(a1[i], b1[jj], acc[i][jj], 0, 0, 0);
        __builtin_amdgcn_s_setprio(0);
        if (t + 1 < T) {
            __builtin_amdgcn_s_waitcnt(WAIT_VM0);
            __builtin_amdgcn_s_barrier();
        }
    }

    // epilogue: prob-scale + bias, scatter to out (fp32)
#pragma unroll
    for (int i = 0; i < 8; ++i) {
        int row0 = wm * 128 + i * 16 + (lane >> 4) * 4;
#pragma unroll
        for (int jj = 0; jj < 4; ++jj) {
            int col = nt * GBN + wn * 64 + jj * 16 + mrow;
            float pb = pre_b[col];
#pragma unroll
            for (int r = 0; r < 4; ++r) {
                int row = row0 + r;
                if (row < mrem) {
                    out[(size_t)s_tok[row] * D_IN + col] = s_p[row] * acc[i][jj][r] + pb;
                }
            }
        }
    }
}

extern "C" void kernel_launch(void* const* d_in, const int* in_sizes, int n_in,
                              void* d_out, int out_size, void* d_ws, size_t ws_size,
                              hipStream_t stream)
{
    const float* act      = (const float*)d_in[0];
    const float* pre_b    = (const float*)d_in[1];
    const float* enc      = (const float*)d_in[2];
    const float* dec      = (const float*)d_in[3];
    const float* router_b = (const float*)d_in[4];
    const float* router   = (const float*)d_in[5];
    float* out = (float*)d_out;

    char* w = (char*)d_ws;
    int* counts  = (int*)w;  w += 256;
    int* offsets = (int*)w;  w += 256;
    int* hist    = (int*)w;  w += ROUTER_BLOCKS * N_EXPERTS * 4;
    int* eidx    = (int*)w;  w += N_TOKENS * 4;
    int* lpos    = (int*)w;  w += N_TOKENS * 4;
    int* order   = (int*)w;  w += N_TOKENS * 4;
    float* prob  = (float*)w; w += N_TOKENS * 4;
    _Float16* act_h  = (_Float16*)w; w += (size_t)N_TOKENS * D_IN * 2;
    _Float16* encT   = (_Float16*)w; w += (size_t)N_EXPERTS * D_IN * EXPERT_DIM * 2;
    _Float16* decT   = (_Float16*)w; w += (size_t)N_EXPERTS * D_IN * EXPERT_DIM * 2;
    _Float16* latent = (_Float16*)w; w += (size_t)(N_TOKENS + GBM) * EXPERT_DIM * 2;

    router_kernel<<<ROUTER_BLOCKS, 256, 0, stream>>>(act, router_b, router, prob, lpos, eidx, hist);
    scan_kernel<<<1, 256, 0, stream>>>(hist, counts, offsets);
    order_kernel<<<N_TOKENS / 256, 256, 0, stream>>>(eidx, lpos, hist, order);

    convert_act<<<N_TOKENS * D_IN / (256 * 8), 256, 0, stream>>>(act, act_h);
    transpose_to_half<<<dim3(EXPERT_DIM / 64, D_IN / 64, N_EXPERTS), 256, 0, stream>>>(enc, encT, D_IN, EXPERT_DIM);
    transpose_to_half<<<dim3(D_IN / 64, EXPERT_DIM / 64, N_EXPERTS), 256, 0, stream>>>(dec, decT, EXPERT_DIM, D_IN);

    encode_kernel<<<4096, 512, 0, stream>>>(act_h, encT, order, counts, offsets, latent);
    decode_kernel<<<1536, 512, 0, stream>>>(latent, decT, order, counts, offsets, prob, pre_b, out);
}